// Round 4
// baseline (4070.176 us; speedup 1.0000x reference)
//
#include <hip/hip_runtime.h>

#define N 50000
#define E 800000
#define H 128
#define G 64
#define OUTC 10
#define L 6
#define EPS 1e-5f

typedef unsigned short ushort_t;

__device__ __forceinline__ void atomAddF(float* p, float v) {
  unsafeAtomicAdd(p, v);   // hw global_atomic_add_f32 on gfx950
}

__device__ __forceinline__ unsigned short f2bf(float f) {
  unsigned u = __float_as_uint(f);
  unsigned r = (u + 0x7FFF + ((u >> 16) & 1)) >> 16;  // RNE
  return (unsigned short)r;
}
__device__ __forceinline__ float bf2f(unsigned short b) {
  return __uint_as_float(((unsigned)b) << 16);
}

// ---------------- init ----------------
__global__ void zero_kernel(int* __restrict__ p, int n) {
  int i = blockIdx.x * blockDim.x + threadIdx.x;
  if (i < n) p[i] = 0;
}

__global__ void deg_count_kernel(const int* __restrict__ dst, int* __restrict__ deg) {
  int e = blockIdx.x * blockDim.x + threadIdx.x;
  if (e < E) atomicAdd(&deg[dst[e]], 1);
}

__global__ void dinv_kernel(const int* __restrict__ deg, float* __restrict__ dinv) {
  int n = blockIdx.x * blockDim.x + threadIdx.x;
  if (n < N) dinv[n] = rsqrtf((float)(deg[n] + 1));
}

// ---------------- 3-phase exclusive scan: deg[N] -> rowptr[N+1] ----------------
#define SCAN_B ((N + 255) / 256)   // 196

__global__ __launch_bounds__(256) void scanA_kernel(const int* __restrict__ deg,
                                                    int* __restrict__ blocksum) {
  __shared__ int red[256];
  int i = blockIdx.x * 256 + threadIdx.x;
  int v = (i < N) ? deg[i] : 0;
  red[threadIdx.x] = v;
  __syncthreads();
  for (int off = 128; off > 0; off >>= 1) {
    if (threadIdx.x < off) red[threadIdx.x] += red[threadIdx.x + off];
    __syncthreads();
  }
  if (threadIdx.x == 0) blocksum[blockIdx.x] = red[0];
}

__global__ __launch_bounds__(256) void scanB_kernel(int* __restrict__ blocksum) {
  __shared__ int sh[256];
  int t = threadIdx.x;
  sh[t] = (t < SCAN_B) ? blocksum[t] : 0;
  __syncthreads();
  for (int off = 1; off < 256; off <<= 1) {
    int v = (t >= off) ? sh[t - off] : 0;
    __syncthreads();
    sh[t] += v;
    __syncthreads();
  }
  if (t < SCAN_B) blocksum[t] = (t == 0) ? 0 : sh[t - 1];  // exclusive
}

__global__ __launch_bounds__(256) void scanC_kernel(const int* __restrict__ deg,
                                                    const int* __restrict__ blocksum,
                                                    int* __restrict__ rowptr) {
  __shared__ int sh[256];
  int i = blockIdx.x * 256 + threadIdx.x;
  int t = threadIdx.x;
  int d = (i < N) ? deg[i] : 0;
  sh[t] = d;
  __syncthreads();
  for (int off = 1; off < 256; off <<= 1) {
    int v = (t >= off) ? sh[t - off] : 0;
    __syncthreads();
    sh[t] += v;
    __syncthreads();
  }
  if (i < N) rowptr[i] = blocksum[blockIdx.x] + sh[t] - d;
  if (i == 0) rowptr[N] = E;
}

__global__ void csr_fill_kernel(const int* __restrict__ src, const int* __restrict__ dst,
                                const int* __restrict__ rowptr,
                                int* __restrict__ cursor, int* __restrict__ csr) {
  int e = blockIdx.x * blockDim.x + threadIdx.x;
  if (e < E) {
    int d = dst[e];
    int pos = rowptr[d] + atomicAdd(&cursor[d], 1);
    csr[pos] = src[e];
  }
}

__global__ void cnt_kernel(const int* __restrict__ batch, float* __restrict__ cnt) {
  __shared__ int lb[G + 1];
  int t = threadIdx.x;  // 128 threads
  if (t <= G) {
    int lo = 0, hi = N;
    while (lo < hi) { int m = (lo + hi) >> 1; if (batch[m] < t) lo = m + 1; else hi = m; }
    lb[t] = lo;
  }
  __syncthreads();
  if (t < G) cnt[t] = (float)(lb[t + 1] - lb[t]);
}

// ---------------- per-layer GEMM: hWs_bf16[row] = dinv[row] * (f(hin)@W)[row] ----------------
// f = identity (bnsums==null) or BN+ReLU fused on load
// block: 256 threads, tile 64 rows x 128 cols, 8x4 per thread
// staging: lane=row mapping -> conflict-free LDS transpose writes
__global__ __launch_bounds__(256) void gemm_layer_kernel(
    const float* __restrict__ hin, const float* __restrict__ W,
    const float* __restrict__ dinv, ushort_t* __restrict__ hWs,
    const float* __restrict__ bnsums, const float* __restrict__ gamma,
    const float* __restrict__ beta)
{
  __shared__ float hsT[128][68];  // [k][row]
  __shared__ float Ws[32][132];   // [k][col]
  const int tid = threadIdx.x;
  const int row0 = blockIdx.x * 64;
  const float invN = 1.0f / (float)N;

  // stage 64x128 input tile, transposed; within a wave: r=lane, kq wave-uniform
#pragma unroll
  for (int i = 0; i < 8; ++i) {
    int idx = i * 256 + tid;
    int r = idx & 63;
    int kq = idx >> 6;          // float4-column 0..31
    int row = row0 + r;
    float4 v = make_float4(0.f, 0.f, 0.f, 0.f);
    if (row < N) v = *(const float4*)&hin[row * H + kq * 4];
    if (bnsums) {
      float4 sm = *(const float4*)&bnsums[kq * 4];
      float4 sq = *(const float4*)&bnsums[128 + kq * 4];
      float4 ga = *(const float4*)&gamma[kq * 4];
      float4 be = *(const float4*)&beta[kq * 4];
      float mu, var;
      mu = sm.x * invN; var = sq.x * invN - mu * mu;
      v.x = fmaxf((v.x - mu) * rsqrtf(var + EPS) * ga.x + be.x, 0.f);
      mu = sm.y * invN; var = sq.y * invN - mu * mu;
      v.y = fmaxf((v.y - mu) * rsqrtf(var + EPS) * ga.y + be.y, 0.f);
      mu = sm.z * invN; var = sq.z * invN - mu * mu;
      v.z = fmaxf((v.z - mu) * rsqrtf(var + EPS) * ga.z + be.z, 0.f);
      mu = sm.w * invN; var = sq.w * invN - mu * mu;
      v.w = fmaxf((v.w - mu) * rsqrtf(var + EPS) * ga.w + be.w, 0.f);
    }
    hsT[kq * 4 + 0][r] = v.x;
    hsT[kq * 4 + 1][r] = v.y;
    hsT[kq * 4 + 2][r] = v.z;
    hsT[kq * 4 + 3][r] = v.w;
  }

  float acc[8][4] = {};
  const int rg = tid >> 5, cg = tid & 31;
  const int r0 = rg * 8, c0 = cg * 4;

  for (int kc = 0; kc < 4; ++kc) {
    __syncthreads();
    for (int s = tid; s < 32 * 32; s += 256) {
      int k = s >> 5, c4 = (s & 31) * 4;
      *(float4*)&Ws[k][c4] = *(const float4*)&W[(kc * 32 + k) * H + c4];
    }
    __syncthreads();
#pragma unroll
    for (int k = 0; k < 32; ++k) {
      float4 a0 = *(const float4*)&hsT[kc * 32 + k][r0];
      float4 a1 = *(const float4*)&hsT[kc * 32 + k][r0 + 4];
      float4 w = *(const float4*)&Ws[k][c0];
      acc[0][0] += a0.x * w.x; acc[0][1] += a0.x * w.y; acc[0][2] += a0.x * w.z; acc[0][3] += a0.x * w.w;
      acc[1][0] += a0.y * w.x; acc[1][1] += a0.y * w.y; acc[1][2] += a0.y * w.z; acc[1][3] += a0.y * w.w;
      acc[2][0] += a0.z * w.x; acc[2][1] += a0.z * w.y; acc[2][2] += a0.z * w.z; acc[2][3] += a0.z * w.w;
      acc[3][0] += a0.w * w.x; acc[3][1] += a0.w * w.y; acc[3][2] += a0.w * w.z; acc[3][3] += a0.w * w.w;
      acc[4][0] += a1.x * w.x; acc[4][1] += a1.x * w.y; acc[4][2] += a1.x * w.z; acc[4][3] += a1.x * w.w;
      acc[5][0] += a1.y * w.x; acc[5][1] += a1.y * w.y; acc[5][2] += a1.y * w.z; acc[5][3] += a1.y * w.w;
      acc[6][0] += a1.z * w.x; acc[6][1] += a1.z * w.y; acc[6][2] += a1.z * w.z; acc[6][3] += a1.z * w.w;
      acc[7][0] += a1.w * w.x; acc[7][1] += a1.w * w.y; acc[7][2] += a1.w * w.z; acc[7][3] += a1.w * w.w;
    }
  }

#pragma unroll
  for (int i = 0; i < 8; ++i) {
    int row = row0 + r0 + i;
    if (row < N) {
      float dv = dinv[row];
      ushort4 o;
      o.x = f2bf(acc[i][0] * dv); o.y = f2bf(acc[i][1] * dv);
      o.z = f2bf(acc[i][2] * dv); o.w = f2bf(acc[i][3] * dv);
      *(ushort4*)&hWs[row * H + c0] = o;
    }
  }
}

// ---------------- CSR gather ----------------
// agg[n] = dinv[n]*(sum_e hWs[src_e] + hWs[n]) + bias
// 32 lanes per node, 4 channels (bf16) per lane; grid exact (N*32/256 = 6250)
// bnsums != null -> also accumulate per-channel sum/sumsq (fused bn_stats)
// pooled != null -> last layer: atomically flush into pooled[batch[n]] instead of agg
__global__ __launch_bounds__(256) void gather_kernel(
    const ushort_t* __restrict__ hWs, const int* __restrict__ csr,
    const int* __restrict__ rowptr, const float* __restrict__ dinv,
    const float* __restrict__ bias, float* __restrict__ agg,
    float* __restrict__ bnsums, const int* __restrict__ batch,
    float* __restrict__ pooled)
{
  __shared__ float red[256][4];
  int t = blockIdx.x * 256 + threadIdx.x;
  int n = t >> 5, c4 = (t & 31) * 4;

  ushort4 us = *(const ushort4*)&hWs[n * H + c4];
  float4 acc = make_float4(bf2f(us.x), bf2f(us.y), bf2f(us.z), bf2f(us.w));
  int e = rowptr[n], end = rowptr[n + 1];
  for (; e + 3 < end; e += 4) {
    int s0 = csr[e], s1 = csr[e + 1], s2 = csr[e + 2], s3 = csr[e + 3];
    ushort4 u0 = *(const ushort4*)&hWs[s0 * H + c4];
    ushort4 u1 = *(const ushort4*)&hWs[s1 * H + c4];
    ushort4 u2 = *(const ushort4*)&hWs[s2 * H + c4];
    ushort4 u3 = *(const ushort4*)&hWs[s3 * H + c4];
    acc.x += (bf2f(u0.x) + bf2f(u1.x)) + (bf2f(u2.x) + bf2f(u3.x));
    acc.y += (bf2f(u0.y) + bf2f(u1.y)) + (bf2f(u2.y) + bf2f(u3.y));
    acc.z += (bf2f(u0.z) + bf2f(u1.z)) + (bf2f(u2.z) + bf2f(u3.z));
    acc.w += (bf2f(u0.w) + bf2f(u1.w)) + (bf2f(u2.w) + bf2f(u3.w));
  }
  for (; e < end; ++e) {
    int s0 = csr[e];
    ushort4 u0 = *(const ushort4*)&hWs[s0 * H + c4];
    acc.x += bf2f(u0.x); acc.y += bf2f(u0.y);
    acc.z += bf2f(u0.z); acc.w += bf2f(u0.w);
  }
  float dn = dinv[n];
  float4 bv = *(const float4*)&bias[c4];
  acc.x = acc.x * dn + bv.x; acc.y = acc.y * dn + bv.y;
  acc.z = acc.z * dn + bv.z; acc.w = acc.w * dn + bv.w;

  if (pooled) {
    float* o = &pooled[batch[n] * H + c4];
    atomAddF(o + 0, acc.x); atomAddF(o + 1, acc.y);
    atomAddF(o + 2, acc.z); atomAddF(o + 3, acc.w);
    return;
  }

  *(float4*)&agg[n * H + c4] = acc;

  // fused bn stats: reduce 8 nodes/block then atomics
  red[threadIdx.x][0] = acc.x; red[threadIdx.x][1] = acc.y;
  red[threadIdx.x][2] = acc.z; red[threadIdx.x][3] = acc.w;
  __syncthreads();
  if (threadIdx.x < 32) {
    float s[4] = {0.f, 0.f, 0.f, 0.f}, q[4] = {0.f, 0.f, 0.f, 0.f};
#pragma unroll
    for (int j = 0; j < 8; ++j) {
#pragma unroll
      for (int c = 0; c < 4; ++c) {
        float v = red[j * 32 + threadIdx.x][c];
        s[c] += v; q[c] += v * v;
      }
    }
    int cc = threadIdx.x * 4;
#pragma unroll
    for (int c = 0; c < 4; ++c) {
      atomAddF(&bnsums[cc + c], s[c]);
      atomAddF(&bnsums[128 + cc + c], q[c]);
    }
  }
}

// ---------------- head ----------------
__global__ void head1_kernel(const float* __restrict__ pooled, const float* __restrict__ cnt,
                             const float* __restrict__ W1, const float* __restrict__ b1,
                             float* __restrict__ z1)
{
  int t = blockIdx.x * 256 + threadIdx.x;  // 8192
  int g = t >> 7, c = t & 127;
  float s = 0.f;
  for (int k = 0; k < H; ++k) s += pooled[g * H + k] * W1[k * H + c];
  z1[t] = s / fmaxf(cnt[g], 1.0f) + b1[c];
}

__global__ void head_bn_kernel(float* __restrict__ z1,
                               const float* __restrict__ gamma, const float* __restrict__ beta)
{
  int c = threadIdx.x;  // 128 threads
  float s = 0.f, q = 0.f;
  for (int g = 0; g < G; ++g) { float v = z1[g * H + c]; s += v; q += v * v; }
  float mu = s / (float)G;
  float var = q / (float)G - mu * mu;
  float rs = rsqrtf(var + EPS);
  float ga = gamma[c], be = beta[c];
  for (int g = 0; g < G; ++g) {
    float v = z1[g * H + c];
    z1[g * H + c] = fmaxf((v - mu) * rs * ga + be, 0.f);
  }
}

__global__ void head2_kernel(const float* __restrict__ z1, const float* __restrict__ W2,
                             const float* __restrict__ b2, float* __restrict__ z2)
{
  int t = blockIdx.x * 256 + threadIdx.x;  // 8192
  int g = t >> 7, c = t & 127;
  float s = b2[c];
  for (int k = 0; k < H; ++k) s += z1[g * H + k] * W2[k * H + c];
  z2[t] = fmaxf(s, 0.f);
}

__global__ void head3_kernel(const float* __restrict__ z2, const float* __restrict__ W3,
                             const float* __restrict__ b3, float* __restrict__ out)
{
  int t = blockIdx.x * 256 + threadIdx.x;
  if (t < G * OUTC) {
    int g = t / OUTC, o = t % OUTC;
    float s = b3[o];
    for (int k = 0; k < H; ++k) s += z2[g * H + k] * W3[k * OUTC + o];
    out[t] = s;
  }
}

extern "C" void kernel_launch(void* const* d_in, const int* in_sizes, int n_in,
                              void* d_out, int out_size, void* d_ws, size_t ws_size,
                              hipStream_t stream) {
  const float* x     = (const float*)d_in[0];
  const int*   ei    = (const int*)d_in[1];
  const int*   srcp  = ei;
  const int*   dstp  = ei + E;
  const int*   batch = (const int*)d_in[2];
  const float* convW = (const float*)d_in[3];
  const float* convb = (const float*)d_in[4];
  const float* bng   = (const float*)d_in[5];
  const float* bnb   = (const float*)d_in[6];
  const float* W1    = (const float*)d_in[7];
  const float* b1    = (const float*)d_in[8];
  const float* hg    = (const float*)d_in[9];
  const float* hb    = (const float*)d_in[10];
  const float* W2    = (const float*)d_in[11];
  const float* b2    = (const float*)d_in[12];
  const float* W3    = (const float*)d_in[13];
  const float* b3    = (const float*)d_in[14];
  float* out = (float*)d_out;

  float*    ws     = (float*)d_ws;
  float*    agg    = ws;                           // N*H f32
  float*    dinv   = agg + (size_t)N * H;          // N
  int*      rowptr = (int*)(dinv + N);             // N+1
  int*      csr    = rowptr + N + 1;               // E
  ushort_t* hWs    = (ushort_t*)(csr + E);         // N*H bf16 (dinv-prescaled)
  int*      deg    = (int*)(hWs + (size_t)N * H);  // N   <- zero region start
  int*      cursor = deg + N;                      // N
  float*    bnsums = (float*)(cursor + N);         // (L-1)*256
  float*    pooled = bnsums + (L - 1) * 256;       // G*H
  float*    cnt    = pooled + G * H;               // G   <- zero region end
  float*    z1     = cnt + G;                      // G*H
  float*    z2     = z1 + G * H;                   // G*H
  int*      bsum   = (int*)(z2 + G * H);           // SCAN_B

  const int zero_words = N + N + (L - 1) * 256 + G * H;
  zero_kernel<<<(zero_words + 255) / 256, 256, 0, stream>>>(deg, zero_words);
  deg_count_kernel<<<(E + 255) / 256, 256, 0, stream>>>(dstp, deg);
  dinv_kernel<<<(N + 255) / 256, 256, 0, stream>>>(deg, dinv);
  scanA_kernel<<<SCAN_B, 256, 0, stream>>>(deg, bsum);
  scanB_kernel<<<1, 256, 0, stream>>>(bsum);
  scanC_kernel<<<SCAN_B, 256, 0, stream>>>(deg, bsum, rowptr);
  csr_fill_kernel<<<(E + 255) / 256, 256, 0, stream>>>(srcp, dstp, rowptr, cursor, csr);
  cnt_kernel<<<1, 128, 0, stream>>>(batch, cnt);

  const float* hin = x;
  for (int l = 0; l < L; ++l) {
    const float* bs = (l == 0) ? nullptr : bnsums + (l - 1) * 256;
    const float* ga = (l == 0) ? nullptr : bng + (size_t)(l - 1) * H;
    const float* be = (l == 0) ? nullptr : bnb + (size_t)(l - 1) * H;
    gemm_layer_kernel<<<(N + 63) / 64, 256, 0, stream>>>(
        hin, convW + (size_t)l * H * H, dinv, hWs, bs, ga, be);
    bool last = (l == L - 1);
    gather_kernel<<<N * 32 / 256, 256, 0, stream>>>(
        hWs, csr, rowptr, dinv, convb + (size_t)l * H, agg,
        last ? nullptr : bnsums + l * 256, batch, last ? pooled : nullptr);
    hin = agg;
  }

  head1_kernel<<<32, 256, 0, stream>>>(pooled, cnt, W1, b1, z1);
  head_bn_kernel<<<1, 128, 0, stream>>>(z1, hg, hb);
  head2_kernel<<<32, 256, 0, stream>>>(z1, W2, b2, z2);
  head3_kernel<<<3, 256, 0, stream>>>(z2, W3, b3, out);
}

// Round 5
// 869.218 us; speedup vs baseline: 4.6826x; 4.6826x over previous
//
#include <hip/hip_runtime.h>

#define N 50000
#define E 800000
#define H 128
#define G 64
#define OUTC 10
#define L 6
#define EPS 1e-5f

typedef unsigned short ushort_t;

__device__ __forceinline__ void atomAddF(float* p, float v) {
  unsafeAtomicAdd(p, v);   // hw global_atomic_add_f32 on gfx950
}

__device__ __forceinline__ unsigned short f2bf(float f) {
  unsigned u = __float_as_uint(f);
  unsigned r = (u + 0x7FFF + ((u >> 16) & 1)) >> 16;  // RNE
  return (unsigned short)r;
}
__device__ __forceinline__ float bf2f(unsigned short b) {
  return __uint_as_float(((unsigned)b) << 16);
}

// ---------------- init ----------------
__global__ void zero_kernel(int* __restrict__ p, int n) {
  int i = blockIdx.x * blockDim.x + threadIdx.x;
  if (i < n) p[i] = 0;
}

__global__ void deg_count_kernel(const int* __restrict__ dst, int* __restrict__ deg) {
  int e = blockIdx.x * blockDim.x + threadIdx.x;
  if (e < E) atomicAdd(&deg[dst[e]], 1);
}

__global__ void dinv_kernel(const int* __restrict__ deg, float* __restrict__ dinv) {
  int n = blockIdx.x * blockDim.x + threadIdx.x;
  if (n < N) dinv[n] = rsqrtf((float)(deg[n] + 1));
}

// ---------------- 3-phase exclusive scan: deg[N] -> rowptr[N+1] ----------------
#define SCAN_B ((N + 255) / 256)   // 196

__global__ __launch_bounds__(256) void scanA_kernel(const int* __restrict__ deg,
                                                    int* __restrict__ blocksum) {
  __shared__ int red[256];
  int i = blockIdx.x * 256 + threadIdx.x;
  int v = (i < N) ? deg[i] : 0;
  red[threadIdx.x] = v;
  __syncthreads();
  for (int off = 128; off > 0; off >>= 1) {
    if (threadIdx.x < off) red[threadIdx.x] += red[threadIdx.x + off];
    __syncthreads();
  }
  if (threadIdx.x == 0) blocksum[blockIdx.x] = red[0];
}

__global__ __launch_bounds__(256) void scanB_kernel(int* __restrict__ blocksum) {
  __shared__ int sh[256];
  int t = threadIdx.x;
  sh[t] = (t < SCAN_B) ? blocksum[t] : 0;
  __syncthreads();
  for (int off = 1; off < 256; off <<= 1) {
    int v = (t >= off) ? sh[t - off] : 0;
    __syncthreads();
    sh[t] += v;
    __syncthreads();
  }
  if (t < SCAN_B) blocksum[t] = (t == 0) ? 0 : sh[t - 1];  // exclusive
}

__global__ __launch_bounds__(256) void scanC_kernel(const int* __restrict__ deg,
                                                    const int* __restrict__ blocksum,
                                                    int* __restrict__ rowptr) {
  __shared__ int sh[256];
  int i = blockIdx.x * 256 + threadIdx.x;
  int t = threadIdx.x;
  int d = (i < N) ? deg[i] : 0;
  sh[t] = d;
  __syncthreads();
  for (int off = 1; off < 256; off <<= 1) {
    int v = (t >= off) ? sh[t - off] : 0;
    __syncthreads();
    sh[t] += v;
    __syncthreads();
  }
  if (i < N) rowptr[i] = blocksum[blockIdx.x] + sh[t] - d;
  if (i == 0) rowptr[N] = E;
}

__global__ void csr_fill_kernel(const int* __restrict__ src, const int* __restrict__ dst,
                                const int* __restrict__ rowptr,
                                int* __restrict__ cursor, int* __restrict__ csr) {
  int e = blockIdx.x * blockDim.x + threadIdx.x;
  if (e < E) {
    int d = dst[e];
    int pos = rowptr[d] + atomicAdd(&cursor[d], 1);
    csr[pos] = src[e];
  }
}

__global__ void cnt_kernel(const int* __restrict__ batch, float* __restrict__ cnt) {
  __shared__ int lb[G + 1];
  int t = threadIdx.x;  // 128 threads
  if (t <= G) {
    int lo = 0, hi = N;
    while (lo < hi) { int m = (lo + hi) >> 1; if (batch[m] < t) lo = m + 1; else hi = m; }
    lb[t] = lo;
  }
  __syncthreads();
  if (t < G) cnt[t] = (float)(lb[t + 1] - lb[t]);
}

// ---------------- per-layer GEMM: hWs_bf16[row] = dinv[row] * (f(hin)@W)[row] ----------------
// f = identity (bnsums==null) or BN+ReLU fused on load
// block: 256 threads, tile 64 rows x 128 cols, 8x4 per thread
// staging: lane=row mapping -> conflict-free LDS transpose writes
__global__ __launch_bounds__(256) void gemm_layer_kernel(
    const float* __restrict__ hin, const float* __restrict__ W,
    const float* __restrict__ dinv, ushort_t* __restrict__ hWs,
    const float* __restrict__ bnsums, const float* __restrict__ gamma,
    const float* __restrict__ beta)
{
  __shared__ float hsT[128][68];  // [k][row]
  __shared__ float Ws[32][132];   // [k][col]
  const int tid = threadIdx.x;
  const int row0 = blockIdx.x * 64;
  const float invN = 1.0f / (float)N;

  // stage 64x128 input tile, transposed; within a wave: r=lane, kq wave-uniform
#pragma unroll
  for (int i = 0; i < 8; ++i) {
    int idx = i * 256 + tid;
    int r = idx & 63;
    int kq = idx >> 6;          // float4-column 0..31
    int row = row0 + r;
    float4 v = make_float4(0.f, 0.f, 0.f, 0.f);
    if (row < N) v = *(const float4*)&hin[row * H + kq * 4];
    if (bnsums) {
      float4 sm = *(const float4*)&bnsums[kq * 4];
      float4 sq = *(const float4*)&bnsums[128 + kq * 4];
      float4 ga = *(const float4*)&gamma[kq * 4];
      float4 be = *(const float4*)&beta[kq * 4];
      float mu, var;
      mu = sm.x * invN; var = sq.x * invN - mu * mu;
      v.x = fmaxf((v.x - mu) * rsqrtf(var + EPS) * ga.x + be.x, 0.f);
      mu = sm.y * invN; var = sq.y * invN - mu * mu;
      v.y = fmaxf((v.y - mu) * rsqrtf(var + EPS) * ga.y + be.y, 0.f);
      mu = sm.z * invN; var = sq.z * invN - mu * mu;
      v.z = fmaxf((v.z - mu) * rsqrtf(var + EPS) * ga.z + be.z, 0.f);
      mu = sm.w * invN; var = sq.w * invN - mu * mu;
      v.w = fmaxf((v.w - mu) * rsqrtf(var + EPS) * ga.w + be.w, 0.f);
    }
    hsT[kq * 4 + 0][r] = v.x;
    hsT[kq * 4 + 1][r] = v.y;
    hsT[kq * 4 + 2][r] = v.z;
    hsT[kq * 4 + 3][r] = v.w;
  }

  float acc[8][4] = {};
  const int rg = tid >> 5, cg = tid & 31;
  const int r0 = rg * 8, c0 = cg * 4;

  for (int kc = 0; kc < 4; ++kc) {
    __syncthreads();
    for (int s = tid; s < 32 * 32; s += 256) {
      int k = s >> 5, c4 = (s & 31) * 4;
      *(float4*)&Ws[k][c4] = *(const float4*)&W[(kc * 32 + k) * H + c4];
    }
    __syncthreads();
#pragma unroll
    for (int k = 0; k < 32; ++k) {
      float4 a0 = *(const float4*)&hsT[kc * 32 + k][r0];
      float4 a1 = *(const float4*)&hsT[kc * 32 + k][r0 + 4];
      float4 w = *(const float4*)&Ws[k][c0];
      acc[0][0] += a0.x * w.x; acc[0][1] += a0.x * w.y; acc[0][2] += a0.x * w.z; acc[0][3] += a0.x * w.w;
      acc[1][0] += a0.y * w.x; acc[1][1] += a0.y * w.y; acc[1][2] += a0.y * w.z; acc[1][3] += a0.y * w.w;
      acc[2][0] += a0.z * w.x; acc[2][1] += a0.z * w.y; acc[2][2] += a0.z * w.z; acc[2][3] += a0.z * w.w;
      acc[3][0] += a0.w * w.x; acc[3][1] += a0.w * w.y; acc[3][2] += a0.w * w.z; acc[3][3] += a0.w * w.w;
      acc[4][0] += a1.x * w.x; acc[4][1] += a1.x * w.y; acc[4][2] += a1.x * w.z; acc[4][3] += a1.x * w.w;
      acc[5][0] += a1.y * w.x; acc[5][1] += a1.y * w.y; acc[5][2] += a1.y * w.z; acc[5][3] += a1.y * w.w;
      acc[6][0] += a1.z * w.x; acc[6][1] += a1.z * w.y; acc[6][2] += a1.z * w.z; acc[6][3] += a1.z * w.w;
      acc[7][0] += a1.w * w.x; acc[7][1] += a1.w * w.y; acc[7][2] += a1.w * w.z; acc[7][3] += a1.w * w.w;
    }
  }

#pragma unroll
  for (int i = 0; i < 8; ++i) {
    int row = row0 + r0 + i;
    if (row < N) {
      float dv = dinv[row];
      ushort4 o;
      o.x = f2bf(acc[i][0] * dv); o.y = f2bf(acc[i][1] * dv);
      o.z = f2bf(acc[i][2] * dv); o.w = f2bf(acc[i][3] * dv);
      *(ushort4*)&hWs[row * H + c0] = o;
    }
  }
}

// ---------------- CSR gather ----------------
// agg[n] = dinv[n]*(sum_e hWs[src_e] + hWs[n]) + bias
// 32 lanes per node, 4 channels (bf16) per lane; grid exact (N*32/256 = 6250)
// no atomics, no LDS, no barrier
__global__ __launch_bounds__(256) void gather_kernel(
    const ushort_t* __restrict__ hWs, const int* __restrict__ csr,
    const int* __restrict__ rowptr, const float* __restrict__ dinv,
    const float* __restrict__ bias, float* __restrict__ agg)
{
  int t = blockIdx.x * 256 + threadIdx.x;
  int n = t >> 5, c4 = (t & 31) * 4;

  ushort4 us = *(const ushort4*)&hWs[n * H + c4];
  float4 acc = make_float4(bf2f(us.x), bf2f(us.y), bf2f(us.z), bf2f(us.w));
  int e = rowptr[n], end = rowptr[n + 1];
  for (; e + 3 < end; e += 4) {
    int s0 = csr[e], s1 = csr[e + 1], s2 = csr[e + 2], s3 = csr[e + 3];
    ushort4 u0 = *(const ushort4*)&hWs[s0 * H + c4];
    ushort4 u1 = *(const ushort4*)&hWs[s1 * H + c4];
    ushort4 u2 = *(const ushort4*)&hWs[s2 * H + c4];
    ushort4 u3 = *(const ushort4*)&hWs[s3 * H + c4];
    acc.x += (bf2f(u0.x) + bf2f(u1.x)) + (bf2f(u2.x) + bf2f(u3.x));
    acc.y += (bf2f(u0.y) + bf2f(u1.y)) + (bf2f(u2.y) + bf2f(u3.y));
    acc.z += (bf2f(u0.z) + bf2f(u1.z)) + (bf2f(u2.z) + bf2f(u3.z));
    acc.w += (bf2f(u0.w) + bf2f(u1.w)) + (bf2f(u2.w) + bf2f(u3.w));
  }
  for (; e < end; ++e) {
    int s0 = csr[e];
    ushort4 u0 = *(const ushort4*)&hWs[s0 * H + c4];
    acc.x += bf2f(u0.x); acc.y += bf2f(u0.y);
    acc.z += bf2f(u0.z); acc.w += bf2f(u0.w);
  }
  float dn = dinv[n];
  float4 bv = *(const float4*)&bias[c4];
  acc.x = acc.x * dn + bv.x; acc.y = acc.y * dn + bv.y;
  acc.z = acc.z * dn + bv.z; acc.w = acc.w * dn + bv.w;
  *(float4*)&agg[n * H + c4] = acc;
}

// ---------------- batchnorm stats: sums[c], sums[128+c] over N rows ----------------
// 391 blocks x 128 rows; block-level partial reduce -> 256 atomics/block
__global__ __launch_bounds__(256) void bn_stats_kernel(
    const float* __restrict__ a, float* __restrict__ sums)
{
  __shared__ float red[256];
  int tid = threadIdx.x;
  int c = tid & 127, half = tid >> 7;
  int r0 = blockIdx.x * 128;
  float s = 0.f, q = 0.f;
  for (int i = 0; i < 64; ++i) {
    int r = r0 + i * 2 + half;
    if (r < N) { float v = a[r * H + c]; s += v; q += v * v; }
  }
  red[tid] = s; __syncthreads();
  float s2 = (half == 0) ? s + red[tid + 128] : 0.f;
  __syncthreads();
  red[tid] = q; __syncthreads();
  if (half == 0) {
    float q2 = q + red[tid + 128];
    atomAddF(&sums[c], s2);
    atomAddF(&sums[128 + c], q2);
  }
}

// ---------------- global mean pool: chunked, run-length accumulate (batch sorted) --------
__global__ __launch_bounds__(256) void pool_kernel(
    const float* __restrict__ h, const int* __restrict__ batch,
    float* __restrict__ pooled /* pre-zeroed */)
{
  int r0 = blockIdx.x * 128;
  int rend = min(r0 + 128, N);
  int c = threadIdx.x & 127, half = threadIdx.x >> 7;
  float acc = 0.f;
  int curg = -1;
  for (int r = r0 + half; r < rend; r += 2) {
    int g = batch[r];
    if (g != curg) {
      if (curg >= 0) atomAddF(&pooled[curg * H + c], acc);
      acc = 0.f; curg = g;
    }
    acc += h[r * H + c];
  }
  if (curg >= 0) atomAddF(&pooled[curg * H + c], acc);
}

// ---------------- head ----------------
__global__ void head1_kernel(const float* __restrict__ pooled, const float* __restrict__ cnt,
                             const float* __restrict__ W1, const float* __restrict__ b1,
                             float* __restrict__ z1)
{
  int t = blockIdx.x * 256 + threadIdx.x;  // 8192
  int g = t >> 7, c = t & 127;
  float s = 0.f;
  for (int k = 0; k < H; ++k) s += pooled[g * H + k] * W1[k * H + c];
  z1[t] = s / fmaxf(cnt[g], 1.0f) + b1[c];
}

__global__ void head_bn_kernel(float* __restrict__ z1,
                               const float* __restrict__ gamma, const float* __restrict__ beta)
{
  int c = threadIdx.x;  // 128 threads
  float s = 0.f, q = 0.f;
  for (int g = 0; g < G; ++g) { float v = z1[g * H + c]; s += v; q += v * v; }
  float mu = s / (float)G;
  float var = q / (float)G - mu * mu;
  float rs = rsqrtf(var + EPS);
  float ga = gamma[c], be = beta[c];
  for (int g = 0; g < G; ++g) {
    float v = z1[g * H + c];
    z1[g * H + c] = fmaxf((v - mu) * rs * ga + be, 0.f);
  }
}

__global__ void head2_kernel(const float* __restrict__ z1, const float* __restrict__ W2,
                             const float* __restrict__ b2, float* __restrict__ z2)
{
  int t = blockIdx.x * 256 + threadIdx.x;  // 8192
  int g = t >> 7, c = t & 127;
  float s = b2[c];
  for (int k = 0; k < H; ++k) s += z1[g * H + k] * W2[k * H + c];
  z2[t] = fmaxf(s, 0.f);
}

__global__ void head3_kernel(const float* __restrict__ z2, const float* __restrict__ W3,
                             const float* __restrict__ b3, float* __restrict__ out)
{
  int t = blockIdx.x * 256 + threadIdx.x;
  if (t < G * OUTC) {
    int g = t / OUTC, o = t % OUTC;
    float s = b3[o];
    for (int k = 0; k < H; ++k) s += z2[g * H + k] * W3[k * OUTC + o];
    out[t] = s;
  }
}

extern "C" void kernel_launch(void* const* d_in, const int* in_sizes, int n_in,
                              void* d_out, int out_size, void* d_ws, size_t ws_size,
                              hipStream_t stream) {
  const float* x     = (const float*)d_in[0];
  const int*   ei    = (const int*)d_in[1];
  const int*   srcp  = ei;
  const int*   dstp  = ei + E;
  const int*   batch = (const int*)d_in[2];
  const float* convW = (const float*)d_in[3];
  const float* convb = (const float*)d_in[4];
  const float* bng   = (const float*)d_in[5];
  const float* bnb   = (const float*)d_in[6];
  const float* W1    = (const float*)d_in[7];
  const float* b1    = (const float*)d_in[8];
  const float* hg    = (const float*)d_in[9];
  const float* hb    = (const float*)d_in[10];
  const float* W2    = (const float*)d_in[11];
  const float* b2    = (const float*)d_in[12];
  const float* W3    = (const float*)d_in[13];
  const float* b3    = (const float*)d_in[14];
  float* out = (float*)d_out;

  float*    ws     = (float*)d_ws;
  float*    agg    = ws;                           // N*H f32
  float*    dinv   = agg + (size_t)N * H;          // N
  int*      rowptr = (int*)(dinv + N);             // N+1
  int*      csr    = rowptr + N + 1;               // E
  ushort_t* hWs    = (ushort_t*)(csr + E);         // N*H bf16 (dinv-prescaled)
  int*      deg    = (int*)(hWs + (size_t)N * H);  // N   <- zero region start
  int*      cursor = deg + N;                      // N
  float*    bnsums = (float*)(cursor + N);         // (L-1)*256
  float*    pooled = bnsums + (L - 1) * 256;       // G*H
  float*    cnt    = pooled + G * H;               // G   <- zero region end
  float*    z1     = cnt + G;                      // G*H
  float*    z2     = z1 + G * H;                   // G*H
  int*      bsum   = (int*)(z2 + G * H);           // SCAN_B

  const int zero_words = N + N + (L - 1) * 256 + G * H;
  zero_kernel<<<(zero_words + 255) / 256, 256, 0, stream>>>(deg, zero_words);
  deg_count_kernel<<<(E + 255) / 256, 256, 0, stream>>>(dstp, deg);
  dinv_kernel<<<(N + 255) / 256, 256, 0, stream>>>(deg, dinv);
  scanA_kernel<<<SCAN_B, 256, 0, stream>>>(deg, bsum);
  scanB_kernel<<<1, 256, 0, stream>>>(bsum);
  scanC_kernel<<<SCAN_B, 256, 0, stream>>>(deg, bsum, rowptr);
  csr_fill_kernel<<<(E + 255) / 256, 256, 0, stream>>>(srcp, dstp, rowptr, cursor, csr);
  cnt_kernel<<<1, 128, 0, stream>>>(batch, cnt);

  const float* hin = x;
  for (int l = 0; l < L; ++l) {
    const float* bs = (l == 0) ? nullptr : bnsums + (l - 1) * 256;
    const float* ga = (l == 0) ? nullptr : bng + (size_t)(l - 1) * H;
    const float* be = (l == 0) ? nullptr : bnb + (size_t)(l - 1) * H;
    gemm_layer_kernel<<<(N + 63) / 64, 256, 0, stream>>>(
        hin, convW + (size_t)l * H * H, dinv, hWs, bs, ga, be);
    gather_kernel<<<N * 32 / 256, 256, 0, stream>>>(
        hWs, csr, rowptr, dinv, convb + (size_t)l * H, agg);
    if (l < L - 1) {
      bn_stats_kernel<<<(N + 127) / 128, 256, 0, stream>>>(agg, bnsums + l * 256);
      hin = agg;
    }
  }

  pool_kernel<<<(N + 127) / 128, 256, 0, stream>>>(agg, batch, pooled);
  head1_kernel<<<32, 256, 0, stream>>>(pooled, cnt, W1, b1, z1);
  head_bn_kernel<<<1, 128, 0, stream>>>(z1, hg, hb);
  head2_kernel<<<32, 256, 0, stream>>>(z1, W2, b2, z2);
  head3_kernel<<<3, 256, 0, stream>>>(z2, W3, b3, out);
}

// Round 6
// 714.098 us; speedup vs baseline: 5.6997x; 1.2172x over previous
//
#include <hip/hip_runtime.h>

#define N 50000
#define E 800000
#define H 128
#define G 64
#define OUTC 10
#define L 6
#define EPS 1e-5f

typedef unsigned short ushort_t;
typedef __attribute__((ext_vector_type(8))) short short8;
typedef __attribute__((ext_vector_type(8))) unsigned short ushort8;
typedef __attribute__((ext_vector_type(4))) float floatx4;

__device__ __forceinline__ void atomAddF(float* p, float v) {
  unsafeAtomicAdd(p, v);   // hw global_atomic_add_f32 on gfx950
}

__device__ __forceinline__ unsigned short f2bf(float f) {
  unsigned u = __float_as_uint(f);
  unsigned r = (u + 0x7FFF + ((u >> 16) & 1)) >> 16;  // RNE
  return (unsigned short)r;
}
__device__ __forceinline__ float bf2f(unsigned short b) {
  return __uint_as_float(((unsigned)b) << 16);
}

// ---------------- init ----------------
__global__ void zero_kernel(int* __restrict__ p, int n) {
  int i = blockIdx.x * blockDim.x + threadIdx.x;
  if (i < n) p[i] = 0;
}

__global__ void deg_count_kernel(const int* __restrict__ dst, int* __restrict__ deg) {
  int e = blockIdx.x * blockDim.x + threadIdx.x;
  if (e < E) atomicAdd(&deg[dst[e]], 1);
}

__global__ void dinv_kernel(const int* __restrict__ deg, float* __restrict__ dinv) {
  int n = blockIdx.x * blockDim.x + threadIdx.x;
  if (n < N) dinv[n] = rsqrtf((float)(deg[n] + 1));
}

// prep: x -> bf16, conv_W -> bf16 transposed WT[l][n][k]
__global__ void prep_kernel(const float* __restrict__ x, const float* __restrict__ convW,
                            ushort_t* __restrict__ xb, ushort_t* __restrict__ WT) {
  int i = blockIdx.x * 256 + threadIdx.x;
  if (i < N * H) {
    xb[i] = f2bf(x[i]);
  } else {
    int j = i - N * H;
    if (j < L * H * H) {
      int l = j >> 14, r = j & 16383;   // H*H = 16384
      int n = r >> 7, k = r & 127;
      WT[j] = f2bf(convW[l * 16384 + k * 128 + n]);
    }
  }
}

// ---------------- 3-phase exclusive scan: deg[N] -> rowptr[N+1] ----------------
#define SCAN_B ((N + 255) / 256)   // 196

__global__ __launch_bounds__(256) void scanA_kernel(const int* __restrict__ deg,
                                                    int* __restrict__ blocksum) {
  __shared__ int red[256];
  int i = blockIdx.x * 256 + threadIdx.x;
  int v = (i < N) ? deg[i] : 0;
  red[threadIdx.x] = v;
  __syncthreads();
  for (int off = 128; off > 0; off >>= 1) {
    if (threadIdx.x < off) red[threadIdx.x] += red[threadIdx.x + off];
    __syncthreads();
  }
  if (threadIdx.x == 0) blocksum[blockIdx.x] = red[0];
}

__global__ __launch_bounds__(256) void scanB_kernel(int* __restrict__ blocksum) {
  __shared__ int sh[256];
  int t = threadIdx.x;
  sh[t] = (t < SCAN_B) ? blocksum[t] : 0;
  __syncthreads();
  for (int off = 1; off < 256; off <<= 1) {
    int v = (t >= off) ? sh[t - off] : 0;
    __syncthreads();
    sh[t] += v;
    __syncthreads();
  }
  if (t < SCAN_B) blocksum[t] = (t == 0) ? 0 : sh[t - 1];  // exclusive
}

__global__ __launch_bounds__(256) void scanC_kernel(const int* __restrict__ deg,
                                                    const int* __restrict__ blocksum,
                                                    int* __restrict__ rowptr) {
  __shared__ int sh[256];
  int i = blockIdx.x * 256 + threadIdx.x;
  int t = threadIdx.x;
  int d = (i < N) ? deg[i] : 0;
  sh[t] = d;
  __syncthreads();
  for (int off = 1; off < 256; off <<= 1) {
    int v = (t >= off) ? sh[t - off] : 0;
    __syncthreads();
    sh[t] += v;
    __syncthreads();
  }
  if (i < N) rowptr[i] = blocksum[blockIdx.x] + sh[t] - d;
  if (i == 0) rowptr[N] = E;
}

__global__ void csr_fill_kernel(const int* __restrict__ src, const int* __restrict__ dst,
                                const int* __restrict__ rowptr,
                                int* __restrict__ cursor, int* __restrict__ csr) {
  int e = blockIdx.x * blockDim.x + threadIdx.x;
  if (e < E) {
    int d = dst[e];
    int pos = rowptr[d] + atomicAdd(&cursor[d], 1);
    csr[pos] = src[e];
  }
}

__global__ void cnt_kernel(const int* __restrict__ batch, float* __restrict__ cnt) {
  __shared__ int lb[G + 1];
  int t = threadIdx.x;  // 128 threads
  if (t <= G) {
    int lo = 0, hi = N;
    while (lo < hi) { int m = (lo + hi) >> 1; if (batch[m] < t) lo = m + 1; else hi = m; }
    lb[t] = lo;
  }
  __syncthreads();
  if (t < G) cnt[t] = (float)(lb[t + 1] - lb[t]);
}

// ---------------- MFMA GEMM: hWs[row] = dinv[row] * (f(Ab)@W)[row], bf16 ----------------
// f = identity (layer 0) or BN+ReLU applied in-register on A fragments.
// LDS-free: A frags from global (L2/L3-resident), B frags from WT (L1-resident).
// block: 256 thr = 4 waves; block tile 64 rows; wave tile 16 rows x 128 cols.
// A layout: A[m=lane&15][k=quad*8+j]; C/D: col=lane&15, row=quad*4+reg.
__global__ __launch_bounds__(256) void gemm_mfma_kernel(
    const ushort_t* __restrict__ Ab, const ushort_t* __restrict__ WT,
    const float* __restrict__ dinv, ushort_t* __restrict__ hWs,
    const float* __restrict__ bnsums, const float* __restrict__ gamma,
    const float* __restrict__ beta)
{
  const int tid = threadIdx.x;
  const int wave = tid >> 6, lane = tid & 63;
  const int quad = lane >> 4, m = lane & 15;
  const int row0 = blockIdx.x * 64 + wave * 16;
  const int arow = min(row0 + m, N - 1);
  const float invN = 1.0f / (float)N;

  short8 afrag[4];
#pragma unroll
  for (int kc = 0; kc < 4; ++kc) {
    ushort8 raw = *(const ushort8*)&Ab[arow * H + kc * 32 + quad * 8];
    if (bnsums) {
      const int k0 = kc * 32 + quad * 8;
#pragma unroll
      for (int j = 0; j < 8; ++j) {
        float s = bnsums[k0 + j], q = bnsums[128 + k0 + j];
        float mu = s * invN;
        float var = q * invN - mu * mu;
        float rs = rsqrtf(var + EPS);
        float sc = gamma[k0 + j] * rs;
        float sh = beta[k0 + j] - mu * sc;
        raw[j] = f2bf(fmaxf(bf2f(raw[j]) * sc + sh, 0.f));
      }
    }
    short8 a;
#pragma unroll
    for (int j = 0; j < 8; ++j) a[j] = (short)raw[j];
    afrag[kc] = a;
  }

  float dv[4];
#pragma unroll
  for (int i = 0; i < 4; ++i) {
    int r = row0 + quad * 4 + i;
    dv[i] = (r < N) ? dinv[r] : 0.f;
  }

  const short* WTs = (const short*)WT;
#pragma unroll
  for (int nt = 0; nt < 8; ++nt) {
    floatx4 acc = {0.f, 0.f, 0.f, 0.f};
#pragma unroll
    for (int kc = 0; kc < 4; ++kc) {
      short8 bfrag = *(const short8*)&WTs[(nt * 16 + m) * H + kc * 32 + quad * 8];
      acc = __builtin_amdgcn_mfma_f32_16x16x32_bf16(afrag[kc], bfrag, acc, 0, 0, 0);
    }
    int col = nt * 16 + m;
#pragma unroll
    for (int i = 0; i < 4; ++i) {
      int r = row0 + quad * 4 + i;
      if (r < N) hWs[r * H + col] = f2bf(acc[i] * dv[i]);
    }
  }
}

// ---------------- CSR gather ----------------
// aggb[n] = bf16( dinv[n]*(sum_e hWs[src_e] + hWs[n]) + bias )
// 16 lanes per node, 8 channels (ushort8 = 16B) per lane; grid exact (N*16/256)
__global__ __launch_bounds__(256) void gather_kernel(
    const ushort_t* __restrict__ hWs, const int* __restrict__ csr,
    const int* __restrict__ rowptr, const float* __restrict__ dinv,
    const float* __restrict__ bias, ushort_t* __restrict__ aggb)
{
  int t = blockIdx.x * 256 + threadIdx.x;
  int n = t >> 4, c8 = (t & 15) * 8;

  ushort8 us = *(const ushort8*)&hWs[n * H + c8];
  float acc[8];
#pragma unroll
  for (int j = 0; j < 8; ++j) acc[j] = bf2f(us[j]);

  int e = rowptr[n], end = rowptr[n + 1];
  for (; e + 3 < end; e += 4) {
    int s0 = csr[e], s1 = csr[e + 1], s2 = csr[e + 2], s3 = csr[e + 3];
    ushort8 u0 = *(const ushort8*)&hWs[s0 * H + c8];
    ushort8 u1 = *(const ushort8*)&hWs[s1 * H + c8];
    ushort8 u2 = *(const ushort8*)&hWs[s2 * H + c8];
    ushort8 u3 = *(const ushort8*)&hWs[s3 * H + c8];
#pragma unroll
    for (int j = 0; j < 8; ++j)
      acc[j] += (bf2f(u0[j]) + bf2f(u1[j])) + (bf2f(u2[j]) + bf2f(u3[j]));
  }
  for (; e < end; ++e) {
    int s0 = csr[e];
    ushort8 u0 = *(const ushort8*)&hWs[s0 * H + c8];
#pragma unroll
    for (int j = 0; j < 8; ++j) acc[j] += bf2f(u0[j]);
  }

  float dn = dinv[n];
  float4 b0 = *(const float4*)&bias[c8];
  float4 b1 = *(const float4*)&bias[c8 + 4];
  float bb[8] = {b0.x, b0.y, b0.z, b0.w, b1.x, b1.y, b1.z, b1.w};
  ushort8 o;
#pragma unroll
  for (int j = 0; j < 8; ++j) o[j] = f2bf(acc[j] * dn + bb[j]);
  *(ushort8*)&aggb[n * H + c8] = o;
}

// ---------------- batchnorm stats over bf16 agg ----------------
// 391 blocks x 128 rows; block partial reduce -> 256 atomics/block
__global__ __launch_bounds__(256) void bn_stats_kernel(
    const ushort_t* __restrict__ a, float* __restrict__ sums)
{
  __shared__ float red[256];
  int tid = threadIdx.x;
  int c = tid & 127, half = tid >> 7;
  int r0 = blockIdx.x * 128;
  float s = 0.f, q = 0.f;
  for (int i = 0; i < 64; ++i) {
    int r = r0 + i * 2 + half;
    if (r < N) { float v = bf2f(a[r * H + c]); s += v; q += v * v; }
  }
  red[tid] = s; __syncthreads();
  float s2 = (half == 0) ? s + red[tid + 128] : 0.f;
  __syncthreads();
  red[tid] = q; __syncthreads();
  if (half == 0) {
    float q2 = q + red[tid + 128];
    atomAddF(&sums[c], s2);
    atomAddF(&sums[128 + c], q2);
  }
}

// ---------------- global mean pool: chunked run-length accumulate (batch sorted) --------
__global__ __launch_bounds__(256) void pool_kernel(
    const ushort_t* __restrict__ h, const int* __restrict__ batch,
    float* __restrict__ pooled /* pre-zeroed */)
{
  int r0 = blockIdx.x * 128;
  int rend = min(r0 + 128, N);
  int c = threadIdx.x & 127, half = threadIdx.x >> 7;
  float acc = 0.f;
  int curg = -1;
  for (int r = r0 + half; r < rend; r += 2) {
    int g = batch[r];
    if (g != curg) {
      if (curg >= 0) atomAddF(&pooled[curg * H + c], acc);
      acc = 0.f; curg = g;
    }
    acc += bf2f(h[r * H + c]);
  }
  if (curg >= 0) atomAddF(&pooled[curg * H + c], acc);
}

// ---------------- head ----------------
__global__ void head1_kernel(const float* __restrict__ pooled, const float* __restrict__ cnt,
                             const float* __restrict__ W1, const float* __restrict__ b1,
                             float* __restrict__ z1)
{
  int t = blockIdx.x * 256 + threadIdx.x;  // 8192
  int g = t >> 7, c = t & 127;
  float s = 0.f;
  for (int k = 0; k < H; ++k) s += pooled[g * H + k] * W1[k * H + c];
  z1[t] = s / fmaxf(cnt[g], 1.0f) + b1[c];
}

__global__ void head_bn_kernel(float* __restrict__ z1,
                               const float* __restrict__ gamma, const float* __restrict__ beta)
{
  int c = threadIdx.x;  // 128 threads
  float s = 0.f, q = 0.f;
  for (int g = 0; g < G; ++g) { float v = z1[g * H + c]; s += v; q += v * v; }
  float mu = s / (float)G;
  float var = q / (float)G - mu * mu;
  float rs = rsqrtf(var + EPS);
  float ga = gamma[c], be = beta[c];
  for (int g = 0; g < G; ++g) {
    float v = z1[g * H + c];
    z1[g * H + c] = fmaxf((v - mu) * rs * ga + be, 0.f);
  }
}

__global__ void head2_kernel(const float* __restrict__ z1, const float* __restrict__ W2,
                             const float* __restrict__ b2, float* __restrict__ z2)
{
  int t = blockIdx.x * 256 + threadIdx.x;  // 8192
  int g = t >> 7, c = t & 127;
  float s = b2[c];
  for (int k = 0; k < H; ++k) s += z1[g * H + k] * W2[k * H + c];
  z2[t] = fmaxf(s, 0.f);
}

__global__ void head3_kernel(const float* __restrict__ z2, const float* __restrict__ W3,
                             const float* __restrict__ b3, float* __restrict__ out)
{
  int t = blockIdx.x * 256 + threadIdx.x;
  if (t < G * OUTC) {
    int g = t / OUTC, o = t % OUTC;
    float s = b3[o];
    for (int k = 0; k < H; ++k) s += z2[g * H + k] * W3[k * OUTC + o];
    out[t] = s;
  }
}

extern "C" void kernel_launch(void* const* d_in, const int* in_sizes, int n_in,
                              void* d_out, int out_size, void* d_ws, size_t ws_size,
                              hipStream_t stream) {
  const float* x     = (const float*)d_in[0];
  const int*   ei    = (const int*)d_in[1];
  const int*   srcp  = ei;
  const int*   dstp  = ei + E;
  const int*   batch = (const int*)d_in[2];
  const float* convW = (const float*)d_in[3];
  const float* convb = (const float*)d_in[4];
  const float* bng   = (const float*)d_in[5];
  const float* bnb   = (const float*)d_in[6];
  const float* W1    = (const float*)d_in[7];
  const float* b1    = (const float*)d_in[8];
  const float* hg    = (const float*)d_in[9];
  const float* hb    = (const float*)d_in[10];
  const float* W2    = (const float*)d_in[11];
  const float* b2    = (const float*)d_in[12];
  const float* W3    = (const float*)d_in[13];
  const float* b3    = (const float*)d_in[14];
  float* out = (float*)d_out;

  const size_t NH2 = (size_t)N * H / 2;            // bf16 buffer size in float units
  float*    ws     = (float*)d_ws;
  ushort_t* xb     = (ushort_t*)ws;                // N*H bf16   (16B aligned)
  ushort_t* aggb   = (ushort_t*)(ws + NH2);        // N*H bf16
  ushort_t* hWs    = (ushort_t*)(ws + 2 * NH2);    // N*H bf16
  ushort_t* WT     = (ushort_t*)(ws + 3 * NH2);    // L*H*H bf16 (49152 floats)
  float*    dinv   = ws + 3 * NH2 + (L * H * H / 2);  // N
  int*      rowptr = (int*)(dinv + N);             // N+1
  int*      csr    = rowptr + N + 1;               // E
  int*      deg    = csr + E;                      // N   <- zero region start
  int*      cursor = deg + N;                      // N
  float*    bnsums = (float*)(cursor + N);         // (L-1)*256
  float*    pooled = bnsums + (L - 1) * 256;       // G*H <- zero region end
  float*    cnt    = pooled + G * H;               // G
  float*    z1     = cnt + G;                      // G*H
  float*    z2     = z1 + G * H;                   // G*H
  int*      bsum   = (int*)(z2 + G * H);           // SCAN_B

  const int zero_words = N + N + (L - 1) * 256 + G * H;
  zero_kernel<<<(zero_words + 255) / 256, 256, 0, stream>>>(deg, zero_words);
  deg_count_kernel<<<(E + 255) / 256, 256, 0, stream>>>(dstp, deg);
  dinv_kernel<<<(N + 255) / 256, 256, 0, stream>>>(deg, dinv);
  scanA_kernel<<<SCAN_B, 256, 0, stream>>>(deg, bsum);
  scanB_kernel<<<1, 256, 0, stream>>>(bsum);
  scanC_kernel<<<SCAN_B, 256, 0, stream>>>(deg, bsum, rowptr);
  csr_fill_kernel<<<(E + 255) / 256, 256, 0, stream>>>(srcp, dstp, rowptr, cursor, csr);
  cnt_kernel<<<1, 128, 0, stream>>>(batch, cnt);
  prep_kernel<<<(N * H + L * H * H + 255) / 256, 256, 0, stream>>>(x, convW, xb, WT);

  for (int l = 0; l < L; ++l) {
    const ushort_t* Ab = (l == 0) ? xb : aggb;
    const float* bs = (l == 0) ? nullptr : bnsums + (l - 1) * 256;
    const float* ga = (l == 0) ? nullptr : bng + (size_t)(l - 1) * H;
    const float* be = (l == 0) ? nullptr : bnb + (size_t)(l - 1) * H;
    gemm_mfma_kernel<<<(N + 63) / 64, 256, 0, stream>>>(
        Ab, WT + (size_t)l * H * H, dinv, hWs, bs, ga, be);
    gather_kernel<<<N * 16 / 256, 256, 0, stream>>>(
        hWs, csr, rowptr, dinv, convb + (size_t)l * H, aggb);
    if (l < L - 1)
      bn_stats_kernel<<<(N + 127) / 128, 256, 0, stream>>>(aggb, bnsums + l * 256);
  }

  pool_kernel<<<(N + 127) / 128, 256, 0, stream>>>(aggb, batch, pooled);
  head1_kernel<<<32, 256, 0, stream>>>(pooled, cnt, W1, b1, z1);
  head_bn_kernel<<<1, 128, 0, stream>>>(z1, hg, hb);
  head2_kernel<<<32, 256, 0, stream>>>(z1, W2, b2, z2);
  head3_kernel<<<3, 256, 0, stream>>>(z2, W3, b3, out);
}